// Round 1
// baseline (2996.650 us; speedup 1.0000x reference)
//
#include <hip/hip_runtime.h>
#include <hip/hip_bf16.h>
#include <cstddef>

// QuarotFP16Linear: out[M,N] = (X[M,K] * sx[M]) @ ((Wq[N,K] - off[N,G]) * ws[N,G])^T
// M=8192 (B*S), N=11008 (OUT), K=4096 (IN), GS=128, G=32.
// Round 0: fused-dequant bf16 MFMA GEMM, 128x128 block tile, BK=32,
// 4 waves/block each computing 64x64 via 4x4 grid of 16x16x32 MFMAs.

typedef __attribute__((ext_vector_type(8))) short short8;    // mfma A/B frag (8 bf16)
typedef __attribute__((ext_vector_type(4))) short short4v;   // 8B LDS store
typedef __attribute__((ext_vector_type(4))) float floatx4;   // mfma C/D frag

#define M_TOT 8192
#define N_TOT 11008
#define K_TOT 4096
#define GSZ   128
#define NG    32

#define BM 128
#define BN 128
#define BK 32
#define LDS_STRIDE 40   // 32 + 8 bf16 pad: keeps 16B alignment for b128, 2-way banks (free)

__device__ __forceinline__ short f2bf_rne(float f) {
    union { float f; unsigned u; } v; v.f = f;
    unsigned r = v.u + 0x7fffu + ((v.u >> 16) & 1u);   // round-to-nearest-even
    return (short)(r >> 16);
}

__global__ __launch_bounds__(256)
void qgemm_kernel(const float* __restrict__ X, const float* __restrict__ SX,
                  const float* __restrict__ Wq, const float* __restrict__ WS,
                  const float* __restrict__ OFW, float* __restrict__ OUT) {
    __shared__ short As[BM * LDS_STRIDE];
    __shared__ short Bs[BN * LDS_STRIDE];

    const int t  = threadIdx.x;
    const int nt = blockIdx.x % (N_TOT / BN);   // 86
    const int mt = blockIdx.x / (N_TOT / BN);   // 64
    const int m0 = mt * BM;
    const int n0 = nt * BN;

    const int lane = t & 63;
    const int wave = t >> 6;
    const int wm   = (wave & 1) * 64;   // wave's M offset in tile
    const int wn   = (wave >> 1) * 64;  // wave's N offset in tile
    const int l15  = lane & 15;
    const int quad = lane >> 4;

    // staging: 8 threads per row, each loads one float4; 4 row-chunks of 32
    const int srow = t >> 3;          // 0..31
    const int scol = (t & 7) * 4;     // 0..28

    floatx4 acc[4][4];
#pragma unroll
    for (int i = 0; i < 4; ++i)
#pragma unroll
        for (int j = 0; j < 4; ++j)
            acc[i][j] = (floatx4)0.0f;

    float ascale[4];
#pragma unroll
    for (int j = 0; j < 4; ++j)
        ascale[j] = SX[m0 + j * 32 + srow];   // per-token activation scale

    for (int g = 0; g < NG; ++g) {
        // quant params for this thread's 4 B-rows, valid for 4 k-tiles (GS=128=4*BK)
        float wsv[4], ofv[4];
#pragma unroll
        for (int j = 0; j < 4; ++j) {
            const int n = n0 + j * 32 + srow;
            wsv[j] = WS[n * NG + g];
            ofv[j] = OFW[n * NG + g];
        }
        for (int kk = 0; kk < GSZ / BK; ++kk) {
            const int k0 = g * GSZ + kk * BK;
            __syncthreads();   // protect LDS from previous iteration's readers
            // ---- stage A: x * sx -> bf16 ----
#pragma unroll
            for (int j = 0; j < 4; ++j) {
                const int r = j * 32 + srow;
                floatx4 v = *(const floatx4*)&X[(size_t)(m0 + r) * K_TOT + k0 + scol];
                const float s = ascale[j];
                short4v b;
                b.x = f2bf_rne(v.x * s);
                b.y = f2bf_rne(v.y * s);
                b.z = f2bf_rne(v.z * s);
                b.w = f2bf_rne(v.w * s);
                *(short4v*)&As[r * LDS_STRIDE + scol] = b;
            }
            // ---- stage B: (w - off) * ws -> bf16 ----
#pragma unroll
            for (int j = 0; j < 4; ++j) {
                const int r = j * 32 + srow;
                floatx4 v = *(const floatx4*)&Wq[(size_t)(n0 + r) * K_TOT + k0 + scol];
                const float sc = wsv[j], of = ofv[j];
                short4v b;
                b.x = f2bf_rne((v.x - of) * sc);
                b.y = f2bf_rne((v.y - of) * sc);
                b.z = f2bf_rne((v.z - of) * sc);
                b.w = f2bf_rne((v.w - of) * sc);
                *(short4v*)&Bs[r * LDS_STRIDE + scol] = b;
            }
            __syncthreads();
            // ---- compute: 4x4 grid of 16x16x32 MFMAs ----
            short8 af[4], bf[4];
#pragma unroll
            for (int i = 0; i < 4; ++i)
                af[i] = *(const short8*)&As[(wm + i * 16 + l15) * LDS_STRIDE + quad * 8];
#pragma unroll
            for (int i = 0; i < 4; ++i)
                bf[i] = *(const short8*)&Bs[(wn + i * 16 + l15) * LDS_STRIDE + quad * 8];
#pragma unroll
            for (int i = 0; i < 4; ++i)
#pragma unroll
                for (int j = 0; j < 4; ++j)
                    acc[i][j] = __builtin_amdgcn_mfma_f32_16x16x32_bf16(af[i], bf[j], acc[i][j], 0, 0, 0);
        }
    }

    // ---- epilogue: D[m = quad*4+r][n = l15] per 16x16 frag ----
#pragma unroll
    for (int i = 0; i < 4; ++i) {
        const int row_base = m0 + wm + i * 16 + quad * 4;
#pragma unroll
        for (int j = 0; j < 4; ++j) {
            const int col = n0 + wn + j * 16 + l15;
#pragma unroll
            for (int r = 0; r < 4; ++r)
                OUT[(size_t)(row_base + r) * N_TOT + col] = acc[i][j][r];
        }
    }
}

extern "C" void kernel_launch(void* const* d_in, const int* in_sizes, int n_in,
                              void* d_out, int out_size, void* d_ws, size_t ws_size,
                              hipStream_t stream) {
    const float* X   = (const float*)d_in[0];   // quantized_x [B,S,IN]
    const float* SX  = (const float*)d_in[1];   // scales_x    [B,S,1]
    const float* Wq  = (const float*)d_in[2];   // weight      [OUT,IN]
    const float* WS  = (const float*)d_in[3];   // weight_scales [OUT,G]
    const float* OFW = (const float*)d_in[4];   // offset_w    [OUT,G]
    float* out = (float*)d_out;

    const int grid = (M_TOT / BM) * (N_TOT / BN);   // 64 * 86 = 5504
    qgemm_kernel<<<grid, 256, 0, stream>>>(X, SX, Wq, WS, OFW, out);
}